// Round 2
// baseline (725.003 us; speedup 1.0000x reference)
//
#include <hip/hip_runtime.h>
#include <math.h>

// Problem constants (B,S,H fixed by reference setup_inputs)
#define BB 32
#define SS 4096
#define HH 1024
#define NCHUNK 32               // S-chunks per batch -> grid 32*32=1024 blocks (4/CU, 16 waves/CU)
#define CHUNK (SS / NCHUNK)     // 128 s-rows per block, 32 per wave (16 iters of 2 rows)
#define NEG_INF9 (-1.0e9f)

__device__ __forceinline__ float wave_reduce_sum(float v) {
#pragma unroll
    for (int off = 32; off > 0; off >>= 1) v += __shfl_xor(v, off, 64);
    return v;
}

// two interleaved butterfly reductions — independent chains overlap latency
__device__ __forceinline__ void wave_reduce_sum2(float& a, float& b) {
#pragma unroll
    for (int off = 32; off > 0; off >>= 1) {
        const float ta = __shfl_xor(a, off, 64);
        const float tb = __shfl_xor(b, off, 64);
        a += ta;
        b += tb;
    }
}

// ---------------- Kernel 1: q = query @ W^T  (per b: [H] = [H] x [H,H]) ----------------
__global__ __launch_bounds__(256) void qproj_kernel(const float* __restrict__ query,
                                                    const float* __restrict__ W,
                                                    float* __restrict__ q) {
    const int b    = blockIdx.y;
    const int wave = threadIdx.x >> 6;
    const int lane = threadIdx.x & 63;

    const float4* qp = (const float4*)(query + (size_t)b * HH);
    float4 qv[4];
#pragma unroll
    for (int r = 0; r < 4; ++r) qv[r] = qp[r * 64 + lane];

    const int obase = blockIdx.x * 64 + wave * 16;  // 16 blocks.x * 64 outputs
    for (int i = 0; i < 16; ++i) {
        const int o = obase + i;
        const float4* wp = (const float4*)(W + (size_t)o * HH);
        float acc = 0.f;
#pragma unroll
        for (int r = 0; r < 4; ++r) {
            const float4 wv = wp[r * 64 + lane];
            acc += wv.x * qv[r].x + wv.y * qv[r].y + wv.z * qv[r].z + wv.w * qv[r].w;
        }
        acc = wave_reduce_sum(acc);
        if (lane == 0) q[(size_t)b * HH + o] = acc;
    }
}

// ---------------- Kernel 2: flash-style fused scores+softmax+context partials ----------------
// One block per (chunk c, batch b). Each wave streams 32 key rows as 16 iterations of a
// ROW PAIR, with explicit double-buffered prefetch so HBM latency overlaps the
// reduce/softmax/accumulate chain. Keys are read exactly once.
__global__ __launch_bounds__(256, 4) void attn_chunk_kernel(const float* __restrict__ q,
                                                            const float* __restrict__ keys,
                                                            const int* __restrict__ mask,
                                                            float* __restrict__ raw_scores,
                                                            float* __restrict__ pm,
                                                            float* __restrict__ pl,
                                                            float* __restrict__ pO) {
    const int b    = blockIdx.y;
    const int c    = blockIdx.x;
    const int wave = threadIdx.x >> 6;
    const int lane = threadIdx.x & 63;

    const float4* qp = (const float4*)(q + (size_t)b * HH);
    float4 qv[4];
#pragma unroll
    for (int r = 0; r < 4; ++r) qv[r] = qp[r * 64 + lane];

    float m = -INFINITY;
    float l = 0.f;
    float4 acc[4];
#pragma unroll
    for (int r = 0; r < 4; ++r) acc[r] = make_float4(0.f, 0.f, 0.f, 0.f);

    const size_t bbase = (size_t)b * SS;
    const int s0 = c * CHUNK + wave * 2;  // this wave's first row pair

    // prefetch first pair
    float4 kva[4], kvb[4];
    {
        const float4* kp0 = (const float4*)(keys + (bbase + s0) * HH);
        const float4* kp1 = (const float4*)(keys + (bbase + s0 + 1) * HH);
#pragma unroll
        for (int r = 0; r < 4; ++r) { kva[r] = kp0[r * 64 + lane]; kvb[r] = kp1[r * 64 + lane]; }
    }

    const int NIT = CHUNK / 8;  // 16 iterations, pair stride 8 rows
    for (int i = 0; i < NIT; ++i) {
        const int s = s0 + 8 * i;

        // ---- prefetch next pair into SEPARATE registers (clamped: last iter re-reads, L1-hit)
        const int sn = (i + 1 < NIT) ? (s + 8) : s;
        float4 kna[4], knb[4];
        {
            const float4* kp0 = (const float4*)(keys + (bbase + sn) * HH);
            const float4* kp1 = (const float4*)(keys + (bbase + sn + 1) * HH);
#pragma unroll
            for (int r = 0; r < 4; ++r) { kna[r] = kp0[r * 64 + lane]; knb[r] = kp1[r * 64 + lane]; }
        }

        // ---- two dots, interleaved reduce
        float sc0 = 0.f, sc1 = 0.f;
#pragma unroll
        for (int r = 0; r < 4; ++r) {
            sc0 += kva[r].x * qv[r].x + kva[r].y * qv[r].y + kva[r].z * qv[r].z + kva[r].w * qv[r].w;
            sc1 += kvb[r].x * qv[r].x + kvb[r].y * qv[r].y + kvb[r].z * qv[r].z + kvb[r].w * qv[r].w;
        }
        wave_reduce_sum2(sc0, sc1);

        const int2 mk = *(const int2*)(mask + bbase + s);  // broadcast 8B load (s is even)
        if (mk.x != 0) sc0 = NEG_INF9;
        if (mk.y != 0) sc1 = NEG_INF9;
        if (lane == 0) *(float2*)(raw_scores + bbase + s) = make_float2(sc0, sc1);

        // ---- online softmax update over the pair
        const float mnew  = fmaxf(m, fmaxf(sc0, sc1));
        const float scale = __expf(m - mnew);  // m=-inf first iter -> 0
        const float p0    = __expf(sc0 - mnew);
        const float p1    = __expf(sc1 - mnew);
        l = l * scale + p0 + p1;
#pragma unroll
        for (int r = 0; r < 4; ++r) {
            acc[r].x = acc[r].x * scale + p0 * kva[r].x + p1 * kvb[r].x;
            acc[r].y = acc[r].y * scale + p0 * kva[r].y + p1 * kvb[r].y;
            acc[r].z = acc[r].z * scale + p0 * kva[r].z + p1 * kvb[r].z;
            acc[r].w = acc[r].w * scale + p0 * kva[r].w + p1 * kvb[r].w;
        }
        m = mnew;

#pragma unroll
        for (int r = 0; r < 4; ++r) { kva[r] = kna[r]; kvb[r] = knb[r]; }
    }

    // ---- combine the 4 waves of this block via LDS
    __shared__ float  sm[4];
    __shared__ float  sl[4];
    __shared__ float4 sO[4][256];  // 16 KB
#pragma unroll
    for (int r = 0; r < 4; ++r) sO[wave][r * 64 + lane] = acc[r];
    if (lane == 0) { sm[wave] = m; sl[wave] = l; }
    __syncthreads();

    const float M = fmaxf(fmaxf(sm[0], sm[1]), fmaxf(sm[2], sm[3]));
    float f[4];
#pragma unroll
    for (int w = 0; w < 4; ++w) f[w] = __expf(sm[w] - M);
    const float L = sl[0] * f[0] + sl[1] * f[1] + sl[2] * f[2] + sl[3] * f[3];

    const int tid = threadIdx.x;
    float4 o = make_float4(0.f, 0.f, 0.f, 0.f);
#pragma unroll
    for (int w = 0; w < 4; ++w) {
        const float4 v = sO[w][tid];
        o.x += f[w] * v.x; o.y += f[w] * v.y; o.z += f[w] * v.z; o.w += f[w] * v.w;
    }
    ((float4*)(pO + ((size_t)b * NCHUNK + c) * HH))[tid] = o;
    if (tid == 0) { pm[b * NCHUNK + c] = M; pl[b * NCHUNK + c] = L; }
}

// ---------------- Kernel 3: merge chunk partials -> context; normalize weights in place ----------------
__global__ __launch_bounds__(256) void combine_kernel(const float* __restrict__ pm,
                                                      const float* __restrict__ pl,
                                                      const float* __restrict__ pO,
                                                      float* __restrict__ context,
                                                      float* __restrict__ weights) {
    const int b   = blockIdx.x;
    const int tid = threadIdx.x;

    float M = -INFINITY;
#pragma unroll
    for (int c = 0; c < NCHUNK; ++c) M = fmaxf(M, pm[b * NCHUNK + c]);
    float fc[NCHUNK];
    float L = 0.f;
#pragma unroll
    for (int c = 0; c < NCHUNK; ++c) {
        fc[c] = __expf(pm[b * NCHUNK + c] - M);
        L += pl[b * NCHUNK + c] * fc[c];
    }
    const float invL = 1.f / L;

    float4 o = make_float4(0.f, 0.f, 0.f, 0.f);
#pragma unroll
    for (int c = 0; c < NCHUNK; ++c) {
        const float4 v = ((const float4*)(pO + ((size_t)b * NCHUNK + c) * HH))[tid];
        const float g = fc[c] * invL;
        o.x += g * v.x; o.y += g * v.y; o.z += g * v.z; o.w += g * v.w;
    }
    ((float4*)(context + (size_t)b * HH))[tid] = o;

    for (int s = tid; s < SS; s += 256) {
        const float sc = weights[(size_t)b * SS + s];
        weights[(size_t)b * SS + s] = __expf(sc - M) * invL;  // masked -1e9 -> exactly 0
    }
}

extern "C" void kernel_launch(void* const* d_in, const int* in_sizes, int n_in,
                              void* d_out, int out_size, void* d_ws, size_t ws_size,
                              hipStream_t stream) {
    const float* query = (const float*)d_in[0];  // [B,1,H]
    const float* keys  = (const float*)d_in[1];  // [B,S,H]
    const int*   mask  = (const int*)d_in[2];    // [B,S] bool->int
    const float* W     = (const float*)d_in[3];  // [H,H]

    float* context = (float*)d_out;                     // B*H floats
    float* weights = (float*)d_out + (size_t)BB * HH;   // B*S floats

    float* q  = (float*)d_ws;                    // B*H
    float* pm = q + (size_t)BB * HH;             // B*NCHUNK
    float* pl = pm + BB * NCHUNK;                // B*NCHUNK
    float* pO = pl + BB * NCHUNK;                // B*NCHUNK*H  (~4.3 MB total ws)

    qproj_kernel<<<dim3(HH / 64, BB), 256, 0, stream>>>(query, W, q);
    attn_chunk_kernel<<<dim3(NCHUNK, BB), 256, 0, stream>>>(q, keys, mask, weights, pm, pl, pO);
    combine_kernel<<<BB, 256, 0, stream>>>(pm, pl, pO, context, weights);
}

// Round 3
// 706.433 us; speedup vs baseline: 1.0263x; 1.0263x over previous
//
#include <hip/hip_runtime.h>
#include <math.h>

// Problem constants (B,S,H fixed by reference setup_inputs)
#define BB 32
#define SS 4096
#define HH 1024
#define NCHUNK 32               // grid 32*32=1024 blocks (4/CU, 16 waves/CU)
#define CHUNK (SS / NCHUNK)     // 128 s-rows per block, 32 per wave
#define NEG_INF9 (-1.0e9f)

__device__ __forceinline__ float wave_reduce_sum(float v) {
#pragma unroll
    for (int off = 32; off > 0; off >>= 1) v += __shfl_xor(v, off, 64);
    return v;
}

// two interleaved butterfly reductions — independent chains overlap latency
__device__ __forceinline__ void wave_reduce_sum2(float& a, float& b) {
#pragma unroll
    for (int off = 32; off > 0; off >>= 1) {
        const float ta = __shfl_xor(a, off, 64);
        const float tb = __shfl_xor(b, off, 64);
        a += ta;
        b += tb;
    }
}

// ---------------- Kernel 1: q = query @ W^T ----------------
__global__ __launch_bounds__(256) void qproj_kernel(const float* __restrict__ query,
                                                    const float* __restrict__ W,
                                                    float* __restrict__ q) {
    const int b    = blockIdx.y;
    const int wave = threadIdx.x >> 6;
    const int lane = threadIdx.x & 63;

    const float4* qp = (const float4*)(query + (size_t)b * HH);
    float4 qv[4];
#pragma unroll
    for (int r = 0; r < 4; ++r) qv[r] = qp[r * 64 + lane];

    const int obase = blockIdx.x * 64 + wave * 16;
    for (int i = 0; i < 16; ++i) {
        const int o = obase + i;
        const float4* wp = (const float4*)(W + (size_t)o * HH);
        float acc = 0.f;
#pragma unroll
        for (int r = 0; r < 4; ++r) {
            const float4 wv = wp[r * 64 + lane];
            acc += wv.x * qv[r].x + wv.y * qv[r].y + wv.z * qv[r].z + wv.w * qv[r].w;
        }
        acc = wave_reduce_sum(acc);
        if (lane == 0) q[(size_t)b * HH + o] = acc;
    }
}

// ---------------- Kernel 2: flash-style fused scores+softmax+context partials ----------------
// One block per (chunk c, batch b). Each wave streams 32 key rows as 16 iters of a row
// PAIR. No manual prefetch: low register pressure (~80 VGPRs) + __restrict__ + unroll(4)
// lets the compiler hoist next-iteration loads across the reduce/softmax chain, and
// 16 waves/CU cover residual latency. Keys are read exactly once.
__global__ __launch_bounds__(256) void attn_chunk_kernel(const float* __restrict__ q,
                                                         const float* __restrict__ keys,
                                                         const int* __restrict__ mask,
                                                         float* __restrict__ raw_scores,
                                                         float* __restrict__ pm,
                                                         float* __restrict__ pl,
                                                         float* __restrict__ pO) {
    const int b    = blockIdx.y;
    const int c    = blockIdx.x;
    const int wave = threadIdx.x >> 6;
    const int lane = threadIdx.x & 63;

    const float4* qp = (const float4*)(q + (size_t)b * HH);
    float4 qv[4];
#pragma unroll
    for (int r = 0; r < 4; ++r) qv[r] = qp[r * 64 + lane];

    float m = -INFINITY;
    float l = 0.f;
    float4 acc[4];
#pragma unroll
    for (int r = 0; r < 4; ++r) acc[r] = make_float4(0.f, 0.f, 0.f, 0.f);

    const size_t bbase = (size_t)b * SS;
    const int s0 = c * CHUNK + wave * 2;  // this wave's first row pair; stride 8

#pragma unroll 4
    for (int i = 0; i < CHUNK / 8; ++i) {
        const int s = s0 + 8 * i;
        const float4* kp0 = (const float4*)(keys + (bbase + s) * HH);
        const float4* kp1 = (const float4*)(keys + (bbase + s + 1) * HH);
        float4 kva[4], kvb[4];
#pragma unroll
        for (int r = 0; r < 4; ++r) { kva[r] = kp0[r * 64 + lane]; kvb[r] = kp1[r * 64 + lane]; }

        float sc0 = 0.f, sc1 = 0.f;
#pragma unroll
        for (int r = 0; r < 4; ++r) {
            sc0 += kva[r].x * qv[r].x + kva[r].y * qv[r].y + kva[r].z * qv[r].z + kva[r].w * qv[r].w;
            sc1 += kvb[r].x * qv[r].x + kvb[r].y * qv[r].y + kvb[r].z * qv[r].z + kvb[r].w * qv[r].w;
        }
        wave_reduce_sum2(sc0, sc1);

        const int2 mk = *(const int2*)(mask + bbase + s);  // broadcast 8B load (s even)
        if (mk.x != 0) sc0 = NEG_INF9;
        if (mk.y != 0) sc1 = NEG_INF9;
        if (lane == 0) *(float2*)(raw_scores + bbase + s) = make_float2(sc0, sc1);

        const float mnew  = fmaxf(m, fmaxf(sc0, sc1));
        const float scale = __expf(m - mnew);  // m=-inf first iter -> 0
        const float p0    = __expf(sc0 - mnew);
        const float p1    = __expf(sc1 - mnew);
        l = l * scale + p0 + p1;
#pragma unroll
        for (int r = 0; r < 4; ++r) {
            acc[r].x = acc[r].x * scale + p0 * kva[r].x + p1 * kvb[r].x;
            acc[r].y = acc[r].y * scale + p0 * kva[r].y + p1 * kvb[r].y;
            acc[r].z = acc[r].z * scale + p0 * kva[r].z + p1 * kvb[r].z;
            acc[r].w = acc[r].w * scale + p0 * kva[r].w + p1 * kvb[r].w;
        }
        m = mnew;
    }

    // ---- combine the 4 waves of this block via LDS
    __shared__ float  sm[4];
    __shared__ float  sl[4];
    __shared__ float4 sO[4][256];  // 16 KB
#pragma unroll
    for (int r = 0; r < 4; ++r) sO[wave][r * 64 + lane] = acc[r];
    if (lane == 0) { sm[wave] = m; sl[wave] = l; }
    __syncthreads();

    const float M = fmaxf(fmaxf(sm[0], sm[1]), fmaxf(sm[2], sm[3]));
    float f[4];
#pragma unroll
    for (int w = 0; w < 4; ++w) f[w] = __expf(sm[w] - M);
    const float L = sl[0] * f[0] + sl[1] * f[1] + sl[2] * f[2] + sl[3] * f[3];

    const int tid = threadIdx.x;
    float4 o = make_float4(0.f, 0.f, 0.f, 0.f);
#pragma unroll
    for (int w = 0; w < 4; ++w) {
        const float4 v = sO[w][tid];
        o.x += f[w] * v.x; o.y += f[w] * v.y; o.z += f[w] * v.z; o.w += f[w] * v.w;
    }
    ((float4*)(pO + ((size_t)b * NCHUNK + c) * HH))[tid] = o;
    if (tid == 0) { pm[b * NCHUNK + c] = M; pl[b * NCHUNK + c] = L; }
}

// ---------------- Kernel 3: merge chunk partials -> context; normalize weights in place ----------------
__global__ __launch_bounds__(256) void combine_kernel(const float* __restrict__ pm,
                                                      const float* __restrict__ pl,
                                                      const float* __restrict__ pO,
                                                      float* __restrict__ context,
                                                      float* __restrict__ weights) {
    const int b   = blockIdx.x;
    const int tid = threadIdx.x;

    float M = -INFINITY;
#pragma unroll
    for (int c = 0; c < NCHUNK; ++c) M = fmaxf(M, pm[b * NCHUNK + c]);
    float fc[NCHUNK];
    float L = 0.f;
#pragma unroll
    for (int c = 0; c < NCHUNK; ++c) {
        fc[c] = __expf(pm[b * NCHUNK + c] - M);
        L += pl[b * NCHUNK + c] * fc[c];
    }
    const float invL = 1.f / L;

    float4 o = make_float4(0.f, 0.f, 0.f, 0.f);
#pragma unroll
    for (int c = 0; c < NCHUNK; ++c) {
        const float4 v = ((const float4*)(pO + ((size_t)b * NCHUNK + c) * HH))[tid];
        const float g = fc[c] * invL;
        o.x += g * v.x; o.y += g * v.y; o.z += g * v.z; o.w += g * v.w;
    }
    ((float4*)(context + (size_t)b * HH))[tid] = o;

    for (int s = tid; s < SS; s += 256) {
        const float sc = weights[(size_t)b * SS + s];
        weights[(size_t)b * SS + s] = __expf(sc - M) * invL;  // masked -1e9 -> exactly 0
    }
}

extern "C" void kernel_launch(void* const* d_in, const int* in_sizes, int n_in,
                              void* d_out, int out_size, void* d_ws, size_t ws_size,
                              hipStream_t stream) {
    const float* query = (const float*)d_in[0];  // [B,1,H]
    const float* keys  = (const float*)d_in[1];  // [B,S,H]
    const int*   mask  = (const int*)d_in[2];    // [B,S] bool->int
    const float* W     = (const float*)d_in[3];  // [H,H]

    float* context = (float*)d_out;                     // B*H floats
    float* weights = (float*)d_out + (size_t)BB * HH;   // B*S floats

    float* q  = (float*)d_ws;                    // B*H
    float* pm = q + (size_t)BB * HH;             // B*NCHUNK
    float* pl = pm + BB * NCHUNK;                // B*NCHUNK
    float* pO = pl + BB * NCHUNK;                // B*NCHUNK*H

    qproj_kernel<<<dim3(HH / 64, BB), 256, 0, stream>>>(query, W, q);
    attn_chunk_kernel<<<dim3(NCHUNK, BB), 256, 0, stream>>>(q, keys, mask, weights, pm, pl, pO);
    combine_kernel<<<BB, 256, 0, stream>>>(pm, pl, pO, context, weights);
}